// Round 3
// baseline (423.105 us; speedup 1.0000x reference)
//
#include <hip/hip_runtime.h>

// EmbeddingBag(mean): V=1e6, D=64, B=16384, L=50.
//
// R3: slice-partitioned windowed gather.
// Evidence so far: R1 (no cross-lane ops) = null vs R0 -> not instruction/
// latency-bound. R2 (warm L3 then gather) = +44us (exactly the warm cost),
// gather unchanged -> a warm L3 does NOT accelerate random 256B reads. The
// wall (~1.4 TB/s effective) is below L2: either DRAM row-activation on
// random rows, or a rate-limited L2-miss->fabric->L3 path. Both are attacked
// by making the random reads hit per-XCD L2, filled by SEQUENTIAL streams:
//   - table split into 8 slices; slice s processed only by blocks with
//     blockIdx%8==s (CDNA4 round-robin block->XCD dispatch heuristic [m09])
//   - slice swept in 1MB windows (<< 4MB per-XCD L2): per window, the
//     slice's 128 blocks prefetch the window cooperatively (sequential,
//     fast path), then gather only in-window entries (random-in-1MB = L2 hits)
//   - per block, bags' indices are pre-bucketed by window via an LDS
//     counting sort (histogram -> prefix -> scatter, atomics on LDS)
//   - accumulators stay in registers across windows (float4 acc[8]/lane,
//     static indexing only - rule #20); per-(slice,bag) partials go to d_ws;
//     a second kernel reduces 8 partials -> mean
// Drift across blocks is self-correcting: leading blocks demand-miss (slow),
// lagging blocks hit warm L2 (fast).
// Prediction: total 369 -> ~220-260 if the L2-window theory holds;
// ~270-300 if only DRAM-page confinement helps (XCD map wrong);
// null (~325-350) => per-request wall invariant -> roofline evidence.

constexpr int kMaxBPG = 8;           // max bags per 16-lane group (B<=16384)
constexpr int kWinShift = 12;        // 4096 rows/window = 1 MB
constexpr int kMaxWin = 32;          // slice_rows <= 131072 (V <= 2^20)
constexpr int kGroupCap = 512;       // kMaxBPG * 64 entries per group

__global__ __launch_bounds__(256, 4) void ebag_gather_sliced(
    const int* __restrict__ indices,    // [T]
    const int* __restrict__ offsets,    // [B]
    const float4* __restrict__ weight4, // [V*16]
    float4* __restrict__ part4,         // [8][B][16] partials (d_ws)
    int B, int T, int V, int bpg)
{
    __shared__ int ssort[16][kGroupCap];     // packed (q<<20)|row, window-sorted
    __shared__ int scnt[16][kMaxWin];        // per-window histogram
    __shared__ int sboff[16][kMaxWin + 1];   // bucket offsets
    __shared__ int scur[16][kMaxWin];        // scatter cursors

    const int tid = threadIdx.x;
    const int grp = tid >> 4;       // 16-lane group within block
    const int col = tid & 15;       // float4 column of the 64-float row
    const int slice = blockIdx.x & 7;    // -> XCD (round-robin heuristic)
    const int lid   = blockIdx.x >> 3;   // block id within slice, 0..127

    const int slice_rows = (V + 7) >> 3;
    const int sbase = slice * slice_rows;
    const int send  = (sbase + slice_rows < V) ? (sbase + slice_rows) : V;
    const int nwin  = (slice_rows + (1 << kWinShift) - 1) >> kWinShift;

    // zero histogram (group-local rows of scnt)
    for (int w = col; w < kMaxWin; w += 16) scnt[grp][w] = 0;

    const int gis = lid * 16 + grp;          // group id within slice, 0..2047
    int bstart[kMaxBPG], bcnt[kMaxBPG];
    #pragma unroll
    for (int q = 0; q < kMaxBPG; ++q) {
        bstart[q] = 0; bcnt[q] = 0;
        if (q < bpg) {
            const int bag = gis * bpg + q;
            if (bag < B) {
                const int s = offsets[bag];
                const int e = (bag + 1 < B) ? offsets[bag + 1] : T;
                bstart[q] = s; bcnt[q] = e - s;
            }
        }
    }
    __syncthreads();

    // Phase A: histogram in-slice entries by window
    #pragma unroll
    for (int q = 0; q < kMaxBPG; ++q) {
        if (q < bpg && bcnt[q] <= 64) {
            for (int j = col; j < bcnt[q]; j += 16) {
                const int idx = indices[bstart[q] + j];
                if (idx >= sbase && idx < send)
                    atomicAdd(&scnt[grp][(idx - sbase) >> kWinShift], 1);
            }
        }
    }
    __syncthreads();

    // Phase B: serial prefix per group (one lane)
    if (col == 0) {
        int run = 0;
        for (int w = 0; w < nwin; ++w) {
            sboff[grp][w] = run;
            scur[grp][w]  = run;
            run += scnt[grp][w];
        }
        sboff[grp][nwin] = run;
    }
    __syncthreads();

    // Phase C: re-read indices (L2-hot) and scatter packed entries
    #pragma unroll
    for (int q = 0; q < kMaxBPG; ++q) {
        if (q < bpg && bcnt[q] <= 64) {
            for (int j = col; j < bcnt[q]; j += 16) {
                const int idx = indices[bstart[q] + j];
                if (idx >= sbase && idx < send) {
                    const int w = (idx - sbase) >> kWinShift;
                    const int pos = atomicAdd(&scur[grp][w], 1);
                    ssort[grp][pos] = (q << 20) | idx;   // V <= 2^20 (host guard)
                }
            }
        }
    }

    float4 acc[kMaxBPG];
    #pragma unroll
    for (int q = 0; q < kMaxBPG; ++q) acc[q] = make_float4(0.f, 0.f, 0.f, 0.f);

    // Oversized bags (count > 64): direct gather once, on slice 0 only.
    if (slice == 0) {
        #pragma unroll
        for (int q = 0; q < kMaxBPG; ++q) {
            if (q < bpg && bcnt[q] > 64) {
                for (int j = 0; j < bcnt[q]; ++j) {
                    const int idx = indices[bstart[q] + j];
                    const float4 v = weight4[(size_t)idx * 16 + col];
                    acc[q].x += v.x; acc[q].y += v.y;
                    acc[q].z += v.z; acc[q].w += v.w;
                }
            }
        }
    }
    __syncthreads();

    // Phase D: per window: cooperative sequential prefetch into (this XCD's)
    // L2, then gather this group's bucket (random within 1MB -> L2 hits).
    const long long gmaxf4 = (long long)V * 16;
    float pfsink = 0.f;
    for (int w = 0; w < nwin; ++w) {
        // this block's 8KB stripe of the 1MB window: 512 float4 / 256 threads
        float4 p0 = make_float4(0.f, 0.f, 0.f, 0.f), p1 = p0;
        {
            const long long winf4 = ((long long)sbase + ((long long)w << kWinShift)) * 16;
            const long long i0 = winf4 + (long long)lid * 512 + tid;
            if (i0 < gmaxf4)        p0 = weight4[i0];
            if (i0 + 256 < gmaxf4)  p1 = weight4[i0 + 256];
        }
        // gather bucket w (entries ~Poisson(1.6) per group per window)
        for (int e = sboff[grp][w]; e < sboff[grp][w + 1]; ++e) {
            const int packed = ssort[grp][e];
            const int q   = packed >> 20;
            const int row = packed & ((1 << 20) - 1);
            const float4 v = weight4[(size_t)row * 16 + col];
            #pragma unroll
            for (int qq = 0; qq < kMaxBPG; ++qq) {  // static acc indexing
                if (qq == q) {
                    acc[qq].x += v.x; acc[qq].y += v.y;
                    acc[qq].z += v.z; acc[qq].w += v.w;
                }
            }
        }
        // consume prefetch (keeps loads live + paces the window)
        pfsink += p0.x + p0.w + p1.x + p1.w;
        __syncthreads();
    }
    asm volatile("" :: "v"(pfsink));  // rule #17: defeat DCE without cost

    // Phase E: write per-(slice,bag) partials (coalesced 256B per group)
    #pragma unroll
    for (int q = 0; q < kMaxBPG; ++q) {
        if (q < bpg) {
            const int bag = gis * bpg + q;
            if (bag < B)
                part4[((size_t)slice * B + bag) * 16 + col] = acc[q];
        }
    }
}

__global__ __launch_bounds__(256) void ebag_reduce(
    const int* __restrict__ offsets,
    const float4* __restrict__ part4,
    float4* __restrict__ out4,
    int B, int T)
{
    const int g = blockIdx.x * blockDim.x + threadIdx.x;
    if (g >= B * 16) return;
    const int bag = g >> 4;
    const int col = g & 15;
    float4 s = make_float4(0.f, 0.f, 0.f, 0.f);
    #pragma unroll
    for (int sl = 0; sl < 8; ++sl) {
        const float4 v = part4[((size_t)sl * B + bag) * 16 + col];
        s.x += v.x; s.y += v.y; s.z += v.z; s.w += v.w;
    }
    const int st = offsets[bag];
    const int en = (bag + 1 < B) ? offsets[bag + 1] : T;
    const int c  = en - st;
    const float inv = 1.0f / (float)((c > 0) ? c : 1);
    s.x *= inv; s.y *= inv; s.z *= inv; s.w *= inv;
    out4[(size_t)bag * 16 + col] = s;
}

// Fallback (R1 kernel): correct for any V / bag sizes / tiny workspace.
constexpr int kBagsPerBlock = 16;
constexpr int kMaxFast = 64;

__global__ __launch_bounds__(256) void ebag_fallback(
    const int* __restrict__ indices,
    const int* __restrict__ offsets,
    const float4* __restrict__ weight4,
    float4* __restrict__ out4,
    int B, int T)
{
    __shared__ int sidx[kBagsPerBlock][kMaxFast + 1];
    const int tid = threadIdx.x;
    const int grp = tid >> 4;
    const int col = tid & 15;
    const int bag = blockIdx.x * kBagsPerBlock + grp;

    int start = 0, count = 0;
    if (bag < B) {
        start = offsets[bag];
        const int end = (bag + 1 < B) ? offsets[bag + 1] : T;
        count = end - start;
    }
    const bool fast = (count <= kMaxFast);
    if (fast) {
        for (int j = col; j < count; j += 16)
            sidx[grp][j] = indices[start + j];
    }
    __syncthreads();

    float4 acc = make_float4(0.f, 0.f, 0.f, 0.f);
    if (fast) {
        const int* sp = sidx[grp];
        for (int j = 0; j < count; ++j) {
            const float4 v = weight4[(size_t)sp[j] * 16 + col];
            acc.x += v.x; acc.y += v.y; acc.z += v.z; acc.w += v.w;
        }
    } else if (count > 0) {
        for (int j = 0; j < count; ++j) {
            const float4 v = weight4[(size_t)indices[start + j] * 16 + col];
            acc.x += v.x; acc.y += v.y; acc.z += v.z; acc.w += v.w;
        }
    }
    if (bag < B) {
        const float inv = 1.0f / (float)((count > 0) ? count : 1);
        acc.x *= inv; acc.y *= inv; acc.z *= inv; acc.w *= inv;
        out4[(size_t)bag * 16 + col] = acc;
    }
}

extern "C" void kernel_launch(void* const* d_in, const int* in_sizes, int n_in,
                              void* d_out, int out_size, void* d_ws, size_t ws_size,
                              hipStream_t stream) {
    const int*   indices = (const int*)d_in[0];
    const int*   offsets = (const int*)d_in[1];
    const float* weight  = (const float*)d_in[2];

    const int T = in_sizes[0];
    const int B = in_sizes[1];
    const int V = in_sizes[2] / 64;          // D = 64 fixed by the problem
    const int bpg = (B + 2047) / 2048;       // bags per 16-lane group
    const size_t ws_need = (size_t)8 * (size_t)B * 256;  // 8 slices x B x 256B

    const bool main_path =
        (in_sizes[2] % 64 == 0) && V >= 1 && V <= (1 << 20) &&
        bpg >= 1 && bpg <= kMaxBPG && ws_size >= ws_need && d_ws != nullptr;

    if (main_path) {
        ebag_gather_sliced<<<1024, 256, 0, stream>>>(
            indices, offsets, (const float4*)weight, (float4*)d_ws, B, T, V, bpg);
        const int rthreads = B * 16;
        ebag_reduce<<<(rthreads + 255) / 256, 256, 0, stream>>>(
            offsets, (const float4*)d_ws, (float4*)d_out, B, T);
    } else {
        const int grid = (B + kBagsPerBlock - 1) / kBagsPerBlock;
        ebag_fallback<<<grid, 256, 0, stream>>>(
            indices, offsets, (const float4*)weight, (float4*)d_out, B, T);
    }
}

// Round 4
// 325.137 us; speedup vs baseline: 1.3013x; 1.3013x over previous
//
#include <hip/hip_runtime.h>

// EmbeddingBag(mean): V=1e6, D=64, B=16384, L=50.
//
// R4: REVERT to the R1 kernel (best known: 324.8us). Session ledger:
//   R0 (64 lanes/bag + shfl)        : 325.8us
//   R1 (16 lanes/bag, LDS indices)  : 324.8us  <- this kernel
//   R2 (+L3 warm pass)              : 368.6us  (+44 = exactly the warm cost; null on gather)
//   R3 (XCD-sliced 1MB L2 windows)  : 423.1us  (sliced kernel 172.7us, sync/VALU-bound)
// Decomposition (closed via R3's visible dispatches):
//   325 = ~155us harness poison-fill (1.024GB @6.6TB/s, in-graph)
//       + ~89us invariant restore/other dispatches
//       + ~80us gather: 155MB HBM / 210MB logical ~= 2 TB/s effective.
// The ~2TB/s random-256B-row service rate is the platform wall, not a kernel
// artifact: removing all cross-lane ops (R1), L3-warming (R2), and L2-window
// confinement (R3 -- whose cache-HIT service rate was itself ~1.8TB/s) all
// failed to move it. Unique-row floor is 143MB -> ~24us at streaming rate;
// the ~56us gap is behind the scattered-access request path, which no tested
// residency tier accelerates.

constexpr int kBagsPerBlock = 16;  // 256 threads = 4 waves x 4 bags/wave
constexpr int kMaxFast = 64;       // fast path when bag count <= 64 (L=50 here)

__global__ __launch_bounds__(256) void FreqAwareEmbedding_kernel(
    const int* __restrict__ indices,    // [T]
    const int* __restrict__ offsets,    // [B]
    const float4* __restrict__ weight4, // [V*16] (V x 64 fp32 as float4)
    float4* __restrict__ out4,          // [B*16]
    int B, int T)
{
    // +1 pad: group bases differ by 65 words -> the 4 concurrent broadcast
    // reads of a wave hit 4 distinct banks.
    __shared__ int sidx[kBagsPerBlock][kMaxFast + 1];

    const int tid = threadIdx.x;
    const int grp = tid >> 4;       // 0..15: bag slot within block
    const int col = tid & 15;       // float4 column within the 64-float row
    const int bag = blockIdx.x * kBagsPerBlock + grp;

    int start = 0, count = 0;
    if (bag < B) {
        start = offsets[bag];
        const int end = (bag + 1 < B) ? offsets[bag + 1] : T;
        count = end - start;
    }

    const bool fast = (count <= kMaxFast);  // uniform within the 16-lane group
    if (fast) {
        // 16 lanes per bag cooperatively stage the bag's indices (coalesced
        // 64B segments per group).
        for (int j = col; j < count; j += 16)
            sidx[grp][j] = indices[start + j];
    }
    __syncthreads();

    float4 acc = make_float4(0.f, 0.f, 0.f, 0.f);

    if (fast) {
        const int* sp = sidx[grp];
        int j = 0;
        // 10-deep pipeline: 10 broadcast LDS reads, then 10 independent 256B
        // row-gathers in flight before the accumulate chain drains them.
        for (; j + 10 <= count; j += 10) {
            int id[10];
            #pragma unroll
            for (int u = 0; u < 10; ++u) id[u] = sp[j + u];
            #pragma unroll
            for (int u = 0; u < 10; ++u) {
                const float4 v = weight4[(size_t)id[u] * 16 + col];
                acc.x += v.x; acc.y += v.y; acc.z += v.z; acc.w += v.w;
            }
        }
        for (; j < count; ++j) {
            const float4 v = weight4[(size_t)sp[j] * 16 + col];
            acc.x += v.x; acc.y += v.y; acc.z += v.z; acc.w += v.w;
        }
    } else if (count > 0) {
        // Generic fallback (not hit for L=50): 16 lanes broadcast-load each
        // index straight from global.
        for (int j = 0; j < count; ++j) {
            const float4 v = weight4[(size_t)indices[start + j] * 16 + col];
            acc.x += v.x; acc.y += v.y; acc.z += v.z; acc.w += v.w;
        }
    }

    if (bag < B) {
        const float inv = 1.0f / (float)((count > 0) ? count : 1);
        acc.x *= inv; acc.y *= inv; acc.z *= inv; acc.w *= inv;
        out4[(size_t)bag * 16 + col] = acc;  // all 16 lanes store: 256B/bag, coalesced
    }
}

extern "C" void kernel_launch(void* const* d_in, const int* in_sizes, int n_in,
                              void* d_out, int out_size, void* d_ws, size_t ws_size,
                              hipStream_t stream) {
    const int*   indices = (const int*)d_in[0];
    const int*   offsets = (const int*)d_in[1];
    const float* weight  = (const float*)d_in[2];

    const int T = in_sizes[0];
    const int B = in_sizes[1];

    const int grid = (B + kBagsPerBlock - 1) / kBagsPerBlock;  // 1024 blocks

    FreqAwareEmbedding_kernel<<<grid, 256, 0, stream>>>(
        indices, offsets, (const float4*)weight, (float4*)d_out, B, T);
}